// Round 1
// baseline (1733.730 us; speedup 1.0000x reference)
//
#include <hip/hip_runtime.h>
#include <hip/hip_bf16.h>

using bf16x8 = __attribute__((ext_vector_type(8))) short;
using f32x4  = __attribute__((ext_vector_type(4))) float;

constexpr int Bn = 32;          // batch
constexpr int Tn = 2048;        // time
constexpr int Fn = 1024;        // feature dim (K)
constexpr int Vn = 256;         // vocab (N)
constexpr int Sn = 256;         // target len
constexpr int Ln = 2 * Sn + 1;  // 513 extended labels
constexpr int Mn = Bn * Tn;     // 65536 GEMM rows

#define NEGF (-1e30f)

__device__ __forceinline__ unsigned int f2bf_u(float x) {
    unsigned int u = __float_as_uint(x);
    return (u + 0x7fffu + ((u >> 16) & 1u)) >> 16;   // RNE to bf16
}
__device__ __forceinline__ unsigned int pack2(float lo, float hi) {
    return f2bf_u(lo) | (f2bf_u(hi) << 16);
}
__device__ __forceinline__ float lae(float a, float b) {   // logaddexp
    float m = fmaxf(a, b);
    float d = fabsf(a - b);
    return m + __logf(1.0f + __expf(-d));
}

// ---------------- GEMM: logits = features @ W^T + bias (bf16 MFMA) ----------
// grid: Mn/128 blocks of 512 threads. BM=128, BN=256(full V), BK=32.
__global__ __launch_bounds__(512) void gemm_logits(
    const float* __restrict__ A,   // [Mn, Fn]
    const float* __restrict__ W,   // [Vn, Fn]  (row-major: this is B^T layout)
    const float* __restrict__ bias,
    float* __restrict__ C)         // [Mn, Vn] fp32
{
    __shared__ unsigned short sA[128 * 32];
    __shared__ unsigned short sB[256 * 32];
    const int tid  = threadIdx.x;
    const int wid  = tid >> 6, lane = tid & 63;
    const int quad = lane >> 4, c16 = lane & 15;
    const int m0 = blockIdx.x * 128;
    const int wm = (wid & 1) * 64;          // 2 m-halves
    const int wn = (wid >> 1) * 64;         // 4 n-quarters

    f32x4 acc[4][4] = {};

    const int srow = tid >> 1;              // B stage row 0..255
    const int sks  = (tid & 1) * 16;        // k segment 0 or 16
    const float* aPtr = A + (size_t)(m0 + (srow & 127)) * Fn + sks;
    const float* bPtr = W + (size_t)srow * Fn + sks;
    unsigned short* sAw = &sA[(srow & 127) * 32 + sks];
    unsigned short* sBw = &sB[srow * 32 + sks];
    const bool doA = (tid < 256);

    for (int k0 = 0; k0 < Fn; k0 += 32) {
        float4 av[4], bv[4];
        if (doA) {
            const float4* ap = reinterpret_cast<const float4*>(aPtr + k0);
            av[0] = ap[0]; av[1] = ap[1]; av[2] = ap[2]; av[3] = ap[3];
        }
        {
            const float4* bp = reinterpret_cast<const float4*>(bPtr + k0);
            bv[0] = bp[0]; bv[1] = bp[1]; bv[2] = bp[2]; bv[3] = bp[3];
        }
        __syncthreads();   // previous iter's LDS reads done
        if (doA) {
            uint4 p;
            p.x = pack2(av[0].x, av[0].y); p.y = pack2(av[0].z, av[0].w);
            p.z = pack2(av[1].x, av[1].y); p.w = pack2(av[1].z, av[1].w);
            *reinterpret_cast<uint4*>(sAw) = p;
            p.x = pack2(av[2].x, av[2].y); p.y = pack2(av[2].z, av[2].w);
            p.z = pack2(av[3].x, av[3].y); p.w = pack2(av[3].z, av[3].w);
            *reinterpret_cast<uint4*>(sAw + 8) = p;
        }
        {
            uint4 p;
            p.x = pack2(bv[0].x, bv[0].y); p.y = pack2(bv[0].z, bv[0].w);
            p.z = pack2(bv[1].x, bv[1].y); p.w = pack2(bv[1].z, bv[1].w);
            *reinterpret_cast<uint4*>(sBw) = p;
            p.x = pack2(bv[2].x, bv[2].y); p.y = pack2(bv[2].z, bv[2].w);
            p.z = pack2(bv[3].x, bv[3].y); p.w = pack2(bv[3].z, bv[3].w);
            *reinterpret_cast<uint4*>(sBw + 8) = p;
        }
        __syncthreads();

        bf16x8 af[4], bf[4];
        #pragma unroll
        for (int mt = 0; mt < 4; ++mt)
            af[mt] = *reinterpret_cast<const bf16x8*>(&sA[(wm + mt * 16 + c16) * 32 + quad * 8]);
        #pragma unroll
        for (int nt = 0; nt < 4; ++nt)
            bf[nt] = *reinterpret_cast<const bf16x8*>(&sB[(wn + nt * 16 + c16) * 32 + quad * 8]);
        #pragma unroll
        for (int mt = 0; mt < 4; ++mt)
            #pragma unroll
            for (int nt = 0; nt < 4; ++nt)
                acc[mt][nt] = __builtin_amdgcn_mfma_f32_16x16x32_bf16(af[mt], bf[nt], acc[mt][nt], 0, 0, 0);
    }

    #pragma unroll
    for (int nt = 0; nt < 4; ++nt) {
        const int n = wn + nt * 16 + c16;
        const float bb = bias[n];
        #pragma unroll
        for (int mt = 0; mt < 4; ++mt) {
            const int mbase = m0 + wm + mt * 16 + quad * 4;
            #pragma unroll
            for (int r = 0; r < 4; ++r)
                C[(size_t)(mbase + r) * Vn + n] = acc[mt][nt][r] + bb;
        }
    }
}

// ---------------- per-row logsumexp over V=256 ------------------------------
__global__ __launch_bounds__(256) void row_lse(
    const float* __restrict__ C, float* __restrict__ lse)
{
    const int row  = blockIdx.x * 4 + (threadIdx.x >> 6);
    const int lane = threadIdx.x & 63;
    float4 v = reinterpret_cast<const float4*>(C + (size_t)row * Vn)[lane];
    float m = fmaxf(fmaxf(v.x, v.y), fmaxf(v.z, v.w));
    #pragma unroll
    for (int off = 32; off >= 1; off >>= 1) m = fmaxf(m, __shfl_xor(m, off, 64));
    float s = __expf(v.x - m) + __expf(v.y - m) + __expf(v.z - m) + __expf(v.w - m);
    #pragma unroll
    for (int off = 32; off >= 1; off >>= 1) s += __shfl_xor(s, off, 64);
    if (lane == 0) lse[row] = m + __logf(s);
}

// ---------------- CTC alpha recursion ---------------------------------------
// 1 block / batch, 4 waves. Wave w owns l in [128w, 128w+128) (w=3: +129).
// Left halo of 64 allows K=32 barrier-free steps (wrongness creeps 2/step).
// Slot layout: l = 128w - 64 + 64*i + j  (i=0..3, j=lane).
__global__ __launch_bounds__(256) void ctc_alpha(
    const float* __restrict__ logits, const float* __restrict__ lse,
    const int* __restrict__ targets, const int* __restrict__ ilen,
    const int* __restrict__ tlen, float* __restrict__ loss_b)
{
    const int b   = blockIdx.x;
    const int tid = threadIdx.x;
    const int w   = tid >> 6, j = tid & 63;
    __shared__ float sAl[Ln];
    const float* lg = logits + (size_t)b * Tn * Vn;
    const float* ls = lse + (size_t)b * Tn;
    const int* tg = targets + b * Sn;
    const int len = ilen[b];
    const int tl  = tlen[b];

    int l[4], e[4];
    bool act[4], own[4], sk[4];
    #pragma unroll
    for (int i = 0; i < 4; ++i) {
        l[i] = 128 * w - 64 + 64 * i + j;
        act[i] = (l[i] >= 0) && (l[i] < Ln) && (i < 3 || w == 3);
        e[i] = 0; sk[i] = false;
        if (act[i] && (l[i] & 1)) {
            int s = l[i] >> 1;
            e[i] = tg[s];
            sk[i] = (s == 0) || (tg[s] != tg[s - 1]);
        }
        own[i] = act[i] && (l[i] >= 128 * w) && (i >= 1);
    }

    // t = 0 init: alpha[0] = lp(blank), alpha[1] = lp(tg[0]), rest NEG
    float a[4];
    const float ls0 = ls[0];
    #pragma unroll
    for (int i = 0; i < 4; ++i)
        a[i] = (act[i] && l[i] < 2) ? (lg[e[i]] - ls0) : NEGF;
    #pragma unroll
    for (int i = 0; i < 4; ++i) if (own[i]) sAl[l[i]] = a[i];
    __syncthreads();

    // prefetch t=1 gathers
    float pl[4], plse;
    {
        const float* row = lg + (size_t)1 * Vn;
        pl[0] = row[e[0]]; pl[1] = row[e[1]]; pl[2] = row[e[2]]; pl[3] = row[e[3]];
        plse = ls[1];
    }
    const int jm1 = (j + 63) & 63, jm2 = (j + 62) & 63;

    int t = 1;
    while (t < Tn) {
        // refresh halo from LDS snapshot
        #pragma unroll
        for (int i = 0; i < 4; ++i)
            if (act[i] && !own[i]) a[i] = sAl[l[i]];
        __syncthreads();           // reads done before anyone stores again
        const int kend = min(t + 32, Tn);
        for (; t < kend; ++t) {
            float cl[4];
            #pragma unroll
            for (int i = 0; i < 4; ++i) cl[i] = pl[i] - plse;
            const int tnext = (t + 1 < Tn) ? t + 1 : t;
            {   // prefetch next row (overlaps compute)
                const float* row = lg + (size_t)tnext * Vn;
                pl[0] = row[e[0]]; pl[1] = row[e[1]]; pl[2] = row[e[2]]; pl[3] = row[e[3]];
                plse = ls[tnext];
            }
            if (t < len) {
                float r1p = NEGF, r2p = NEGF;   // rotated vals of slot i-1
                float na[4];
                #pragma unroll
                for (int i = 0; i < 4; ++i) {
                    float r1 = __shfl(a[i], jm1, 64);
                    float r2 = __shfl(a[i], jm2, 64);
                    float a1 = (j == 0) ? r1p : r1;
                    float a2 = (j < 2) ? r2p : r2;
                    a2 = sk[i] ? a2 : NEGF;
                    float v = cl[i] + lae(lae(a[i], a1), a2);
                    na[i] = act[i] ? v : NEGF;
                    r1p = r1; r2p = r2;
                }
                #pragma unroll
                for (int i = 0; i < 4; ++i) a[i] = na[i];
            }
        }
        #pragma unroll
        for (int i = 0; i < 4; ++i) if (own[i]) sAl[l[i]] = a[i];
        __syncthreads();
    }

    if (tid == 0) {
        float e1 = sAl[2 * tl];
        float e2 = sAl[2 * tl - 1];
        loss_b[b] = -lae(e1, e2) / (float)tl;
    }
}

// ---------------- final mean over batch -------------------------------------
__global__ void final_reduce(const float* __restrict__ loss_b, float* __restrict__ out)
{
    const int lane = threadIdx.x;
    float v = (lane < Bn) ? loss_b[lane] : 0.0f;
    #pragma unroll
    for (int off = 32; off >= 1; off >>= 1) v += __shfl_xor(v, off, 64);
    if (lane == 0) out[0] = v * (1.0f / Bn);
}

extern "C" void kernel_launch(void* const* d_in, const int* in_sizes, int n_in,
                              void* d_out, int out_size, void* d_ws, size_t ws_size,
                              hipStream_t stream) {
    const float* feat = (const float*)d_in[0];
    const float* W    = (const float*)d_in[1];
    const float* bias = (const float*)d_in[2];
    const int* tgt    = (const int*)d_in[3];
    const int* il     = (const int*)d_in[4];
    const int* tl     = (const int*)d_in[5];
    float* out = (float*)d_out;

    char* ws = (char*)d_ws;
    float* logits = (float*)ws;                                    // 64 MB
    float* lse    = (float*)(ws + (size_t)Mn * Vn * sizeof(float));
    float* lossb  = (float*)(ws + (size_t)Mn * Vn * sizeof(float) + (size_t)Mn * sizeof(float));

    gemm_logits<<<dim3(Mn / 128), 512, 0, stream>>>(feat, W, bias, logits);
    row_lse<<<Mn / 4, 256, 0, stream>>>(logits, lse);
    ctc_alpha<<<Bn, 256, 0, stream>>>(logits, lse, tgt, il, tl, lossb);
    final_reduce<<<1, 64, 0, stream>>>(lossb, out);
}

// Round 3
// 839.353 us; speedup vs baseline: 2.0656x; 2.0656x over previous
//
#include <hip/hip_runtime.h>
#include <hip/hip_bf16.h>

using bf16x8 = __attribute__((ext_vector_type(8))) short;
using f32x4  = __attribute__((ext_vector_type(4))) float;

constexpr int Bn = 32;          // batch
constexpr int Tn = 2048;        // time
constexpr int Fn = 1024;        // feature dim (K)
constexpr int Vn = 256;         // vocab (N)
constexpr int Sn = 256;         // target len
constexpr int Ln = 2 * Sn + 1;  // 513 extended labels
constexpr int Mn = Bn * Tn;     // 65536 GEMM rows
constexpr int Lpad = 520;       // padded G row (float4-aligned)
constexpr int OWN = 132;        // l-slots owned per wave (4 waves, 4*132=528>=513)
constexpr int DQ = 8;           // prefetch pipeline depth

#define NEGF (-1e30f)

__device__ __forceinline__ float exp2fast(float x) { return __builtin_amdgcn_exp2f(x); }
__device__ __forceinline__ float log2fast(float x) { return __builtin_amdgcn_logf(x); }

__device__ __forceinline__ unsigned int f2bf_u(float x) {
    unsigned int u = __float_as_uint(x);
    return (u + 0x7fffu + ((u >> 16) & 1u)) >> 16;   // RNE to bf16
}
__device__ __forceinline__ unsigned int pack2(float lo, float hi) {
    return f2bf_u(lo) | (f2bf_u(hi) << 16);
}
// log-add-exp in log2 domain (inputs/outputs are log2-probabilities)
__device__ __forceinline__ float lae2(float x, float y) {
    float m = fmaxf(x, y);
    float s = exp2fast(x - m) + exp2fast(y - m);
    return m + log2fast(s);
}
__device__ __forceinline__ float lae3(float x, float y, float z) {
    float m = fmaxf(fmaxf(x, y), z);          // v_max3_f32
    float s = exp2fast(x - m) + exp2fast(y - m) + exp2fast(z - m);
    return m + log2fast(s);
}

// ---------------- GEMM: logits = features @ W^T + bias (bf16 MFMA) ----------
__global__ __launch_bounds__(512) void gemm_logits(
    const float* __restrict__ A,   // [Mn, Fn]
    const float* __restrict__ W,   // [Vn, Fn]
    const float* __restrict__ bias,
    float* __restrict__ C)         // [Mn, Vn] fp32
{
    __shared__ unsigned short sA[128 * 32];
    __shared__ unsigned short sB[256 * 32];
    const int tid  = threadIdx.x;
    const int wid  = tid >> 6, lane = tid & 63;
    const int quad = lane >> 4, c16 = lane & 15;
    const int m0 = blockIdx.x * 128;
    const int wm = (wid & 1) * 64;
    const int wn = (wid >> 1) * 64;

    f32x4 acc[4][4] = {};

    const int srow = tid >> 1;
    const int sks  = (tid & 1) * 16;
    const float* aPtr = A + (size_t)(m0 + (srow & 127)) * Fn + sks;
    const float* bPtr = W + (size_t)srow * Fn + sks;
    unsigned short* sAw = &sA[(srow & 127) * 32 + sks];
    unsigned short* sBw = &sB[srow * 32 + sks];
    const bool doA = (tid < 256);

    for (int k0 = 0; k0 < Fn; k0 += 32) {
        float4 av[4], bv[4];
        if (doA) {
            const float4* ap = reinterpret_cast<const float4*>(aPtr + k0);
            av[0] = ap[0]; av[1] = ap[1]; av[2] = ap[2]; av[3] = ap[3];
        }
        {
            const float4* bp = reinterpret_cast<const float4*>(bPtr + k0);
            bv[0] = bp[0]; bv[1] = bp[1]; bv[2] = bp[2]; bv[3] = bp[3];
        }
        __syncthreads();
        if (doA) {
            uint4 p;
            p.x = pack2(av[0].x, av[0].y); p.y = pack2(av[0].z, av[0].w);
            p.z = pack2(av[1].x, av[1].y); p.w = pack2(av[1].z, av[1].w);
            *reinterpret_cast<uint4*>(sAw) = p;
            p.x = pack2(av[2].x, av[2].y); p.y = pack2(av[2].z, av[2].w);
            p.z = pack2(av[3].x, av[3].y); p.w = pack2(av[3].z, av[3].w);
            *reinterpret_cast<uint4*>(sAw + 8) = p;
        }
        {
            uint4 p;
            p.x = pack2(bv[0].x, bv[0].y); p.y = pack2(bv[0].z, bv[0].w);
            p.z = pack2(bv[1].x, bv[1].y); p.w = pack2(bv[1].z, bv[1].w);
            *reinterpret_cast<uint4*>(sBw) = p;
            p.x = pack2(bv[2].x, bv[2].y); p.y = pack2(bv[2].z, bv[2].w);
            p.z = pack2(bv[3].x, bv[3].y); p.w = pack2(bv[3].z, bv[3].w);
            *reinterpret_cast<uint4*>(sBw + 8) = p;
        }
        __syncthreads();

        bf16x8 af[4], bf[4];
        #pragma unroll
        for (int mt = 0; mt < 4; ++mt)
            af[mt] = *reinterpret_cast<const bf16x8*>(&sA[(wm + mt * 16 + c16) * 32 + quad * 8]);
        #pragma unroll
        for (int nt = 0; nt < 4; ++nt)
            bf[nt] = *reinterpret_cast<const bf16x8*>(&sB[(wn + nt * 16 + c16) * 32 + quad * 8]);
        #pragma unroll
        for (int mt = 0; mt < 4; ++mt)
            #pragma unroll
            for (int nt = 0; nt < 4; ++nt)
                acc[mt][nt] = __builtin_amdgcn_mfma_f32_16x16x32_bf16(af[mt], bf[nt], acc[mt][nt], 0, 0, 0);
    }

    #pragma unroll
    for (int nt = 0; nt < 4; ++nt) {
        const int n = wn + nt * 16 + c16;
        const float bb = bias[n];
        #pragma unroll
        for (int mt = 0; mt < 4; ++mt) {
            const int mbase = m0 + wm + mt * 16 + quad * 4;
            #pragma unroll
            for (int r = 0; r < 4; ++r)
                C[(size_t)(mbase + r) * Vn + n] = acc[mt][nt][r] + bb;
        }
    }
}

// -------- gather+normalize: G[m][l] = (logit[m][ext[l]] - lse[m]) * log2e ----
// One wave per row m; 4 rows per 256-thread block.
__global__ __launch_bounds__(256) void gather_g(
    const float* __restrict__ C, const int* __restrict__ targets,
    float* __restrict__ G)
{
    const int wv   = threadIdx.x >> 6;
    const int lane = threadIdx.x & 63;
    const int row  = blockIdx.x * 4 + wv;            // m = b*Tn + t
    const int b    = row >> 11;                      // Tn = 2048
    const int* tg  = targets + b * Sn;
    __shared__ float sRow[4][256];

    const float L2E = 1.4426950408889634f;
    float4 v = reinterpret_cast<const float4*>(C + (size_t)row * Vn)[lane];
    float4 x;
    x.x = v.x * L2E; x.y = v.y * L2E; x.z = v.z * L2E; x.w = v.w * L2E;
    float m = fmaxf(fmaxf(x.x, x.y), fmaxf(x.z, x.w));
    #pragma unroll
    for (int off = 32; off >= 1; off >>= 1) m = fmaxf(m, __shfl_xor(m, off, 64));
    float s = exp2fast(x.x - m) + exp2fast(x.y - m) + exp2fast(x.z - m) + exp2fast(x.w - m);
    #pragma unroll
    for (int off = 32; off >= 1; off >>= 1) s += __shfl_xor(s, off, 64);
    const float lse2 = m + log2fast(s);

    float4 y;
    y.x = x.x - lse2; y.y = x.y - lse2; y.z = x.z - lse2; y.w = x.w - lse2;
    reinterpret_cast<float4*>(sRow[wv])[lane] = y;   // same-wave LDS, no barrier

    float* Grow = G + (size_t)row * Lpad;
    #pragma unroll
    for (int q = 0; q < 8; ++q) {
        int l = q * 64 + lane;
        int e = 0;
        if (l & 1) e = tg[l >> 1];
        Grow[l] = sRow[wv][e];
    }
    if (lane == 0) Grow[512] = sRow[wv][0];          // l=512 is blank
}

// ---------------- CTC alpha recursion (log2 domain) --------------------------
// 1 block/batch, 4 waves. Lane j of wave w holds 4 consecutive l's:
// l = OWN*w - 64 + 4*j + i. Left halo of 64 slots -> 32 barrier-free steps.
// Slots 0,2 of each lane have even l (blank): only {l, l-1} transitions.
// Slots 1,3 have odd l (label): {l, l-1, l-2(skip-gated)}.
__global__ __launch_bounds__(256) void ctc_alpha(
    const float* __restrict__ G, const int* __restrict__ targets,
    const int* __restrict__ ilen, const int* __restrict__ tlen,
    float* __restrict__ loss_b)
{
    const int b = blockIdx.x, tid = threadIdx.x;
    const int w = tid >> 6, j = tid & 63;
    __shared__ float sAl[Ln];
    const float* Gb = G + (size_t)b * Tn * Lpad;
    const int* tg = targets + b * Sn;
    const int len = ilen[b];
    const int tl  = tlen[b];
    const int lbase = OWN * w - 64 + 4 * j;
    const int cbase = min(max(lbase, 0), Lpad - 4);

    bool act[4], own[4];
    #pragma unroll
    for (int i = 0; i < 4; ++i) {
        int l = lbase + i;
        act[i] = (l >= 0) && (l < Ln);
        own[i] = act[i] && (l >= OWN * w) && (l < OWN * (w + 1));
    }
    bool sk1 = false, sk3 = false;   // skip-transition allowed (odd slots only)
    if (act[1]) { int s = (lbase + 1) >> 1; sk1 = (s == 0) || (tg[s] != tg[s - 1]); }
    if (act[3]) { int s = (lbase + 3) >> 1; sk3 = (s == 0) || (tg[s] != tg[s - 1]); }

    // t = 0 init from G row 0 (log2 domain)
    float a[4];
    {
        float4 g0 = *reinterpret_cast<const float4*>(Gb + cbase);
        float gv[4] = {g0.x, g0.y, g0.z, g0.w};
        #pragma unroll
        for (int i = 0; i < 4; ++i)
            a[i] = (act[i] && (lbase + i) < 2) ? gv[i] : NEGF;
    }
    #pragma unroll
    for (int i = 0; i < 4; ++i) if (own[i]) sAl[lbase + i] = a[i];
    __syncthreads();
    #pragma unroll
    for (int i = 0; i < 4; ++i) if (act[i] && !own[i]) a[i] = sAl[lbase + i];
    __syncthreads();

    // preload pipeline for t = 1..DQ
    float4 pl[DQ];
    #pragma unroll
    for (int d = 0; d < DQ; ++d) {
        int tq = min(1 + d, Tn - 1);
        pl[d] = *reinterpret_cast<const float4*>(Gb + (size_t)tq * Lpad + cbase);
    }

    const int jm1 = (j + 63) & 63;
    int t = 1;
    for (int chunk = 0; chunk < 64; ++chunk) {
        #pragma unroll
        for (int kk = 0; kk < 32; ++kk, ++t) {
            const int pidx = kk & (DQ - 1);
            float4 g = pl[pidx];
            int tq = min(t + DQ, Tn - 1);
            pl[pidx] = *reinterpret_cast<const float4*>(Gb + (size_t)tq * Lpad + cbase);
            float p3 = __shfl(a[3], jm1, 64);     // old alpha at (slot0's l)-1
            if (j == 0) p3 = NEGF;
            if (t < len) {
                float n0 = g.x + lae2(a[0], p3);
                float n1 = g.y + lae3(a[1], a[0], sk1 ? p3 : NEGF);
                float n2 = g.z + lae2(a[2], a[1]);
                float n3 = g.w + lae3(a[3], a[2], sk3 ? a[1] : NEGF);
                a[0] = act[0] ? n0 : NEGF;
                a[1] = act[1] ? n1 : NEGF;
                a[2] = act[2] ? n2 : NEGF;
                a[3] = act[3] ? n3 : NEGF;
            }
        }
        #pragma unroll
        for (int i = 0; i < 4; ++i) if (own[i]) sAl[lbase + i] = a[i];
        __syncthreads();
        #pragma unroll
        for (int i = 0; i < 4; ++i) if (act[i] && !own[i]) a[i] = sAl[lbase + i];
        __syncthreads();
    }

    if (tid == 0) {
        float e1 = sAl[2 * tl];
        float e2 = sAl[2 * tl - 1];
        loss_b[b] = -0.6931471805599453f * lae2(e1, e2) / (float)tl;
    }
}

// ---------------- final mean over batch -------------------------------------
__global__ void final_reduce(const float* __restrict__ loss_b, float* __restrict__ out)
{
    const int lane = threadIdx.x;
    float v = (lane < Bn) ? loss_b[lane] : 0.0f;
    #pragma unroll
    for (int off = 32; off >= 1; off >>= 1) v += __shfl_xor(v, off, 64);
    if (lane == 0) out[0] = v * (1.0f / Bn);
}

extern "C" void kernel_launch(void* const* d_in, const int* in_sizes, int n_in,
                              void* d_out, int out_size, void* d_ws, size_t ws_size,
                              hipStream_t stream) {
    const float* feat = (const float*)d_in[0];
    const float* W    = (const float*)d_in[1];
    const float* bias = (const float*)d_in[2];
    const int* tgt    = (const int*)d_in[3];
    const int* il     = (const int*)d_in[4];
    const int* tl     = (const int*)d_in[5];
    float* out = (float*)d_out;

    char* ws = (char*)d_ws;
    float* logits = (float*)ws;                                      // 64 MB
    size_t off_g  = (size_t)Mn * Vn * sizeof(float);
    float* G      = (float*)(ws + off_g);                            // 136 MB
    float* lossb  = (float*)(ws + off_g + (size_t)Mn * Lpad * sizeof(float));

    gemm_logits<<<dim3(Mn / 128), 512, 0, stream>>>(feat, W, bias, logits);
    gather_g<<<Mn / 4, 256, 0, stream>>>(logits, tgt, G);
    ctc_alpha<<<Bn, 256, 0, stream>>>(G, tgt, il, tl, lossb);
    final_reduce<<<1, 64, 0, stream>>>(lossb, out);
}